// Round 1
// baseline (1130.561 us; speedup 1.0000x reference)
//
#include <hip/hip_runtime.h>
#include <math.h>

#define NKPT 17
#define MM   10
#define DD   768
#define NN   131072
#define CC   (NKPT*MM)   // 170
#define CHUNKS 16
#define GCH    8
#define BR   128
#define BC   192
#define KC   32
#define EROWS 64

// ---------------- proto norms + normalized protos ----------------
__global__ __launch_bounds__(256) void k_proto_norm(const float* __restrict__ protos,
                                                    float* __restrict__ pn) {
    int c = blockIdx.x;           // 0..169
    int t = threadIdx.x;          // 256
    const float* row = protos + (size_t)c * DD;
    float v0 = row[t], v1 = row[t + 256], v2 = row[t + 512];
    double ss = (double)v0 * v0 + (double)v1 * v1 + (double)v2 * v2;
    __shared__ double red[256];
    red[t] = ss; __syncthreads();
    for (int s = 128; s > 0; s >>= 1) { if (t < s) red[t] += red[t + s]; __syncthreads(); }
    float invf = (float)(1.0 / fmax(sqrt(red[0]), 1e-12));
    pn[(size_t)c * DD + t]       = v0 * invf;
    pn[(size_t)c * DD + t + 256] = v1 * invf;
    pn[(size_t)c * DD + t + 512] = v2 * invf;
}

// ---------------- feat inverse norms ----------------
__global__ __launch_bounds__(64) void k_feat_norm(const float* __restrict__ feats,
                                                  float* __restrict__ inv_f) {
    int n = blockIdx.x;
    int l = threadIdx.x;          // 64
    const float4* r4 = (const float4*)(feats + (size_t)n * DD);
    float4 a = r4[l], b = r4[l + 64], c = r4[l + 128];
    double ss = (double)a.x*a.x + (double)a.y*a.y + (double)a.z*a.z + (double)a.w*a.w
              + (double)b.x*b.x + (double)b.y*b.y + (double)b.z*b.z + (double)b.w*b.w
              + (double)c.x*c.x + (double)c.y*c.y + (double)c.z*c.z + (double)c.w*c.w;
    #pragma unroll
    for (int off = 32; off > 0; off >>= 1) ss += __shfl_down(ss, off);
    if (l == 0) inv_f[n] = (float)(1.0 / fmax(sqrt(ss), 1e-12));
}

// ---------------- class histogram ----------------
__global__ __launch_bounds__(256) void k_hist(const int* __restrict__ gt,
                                              int* __restrict__ counts) {
    __shared__ int c[NKPT];
    int t = threadIdx.x;
    if (t < NKPT) c[t] = 0;
    __syncthreads();
    for (int i = blockIdx.x * blockDim.x + t; i < NN; i += gridDim.x * blockDim.x)
        atomicAdd(&c[gt[i]], 1);
    __syncthreads();
    if (t < NKPT) atomicAdd(&counts[t], c[t]);
}

__global__ void k_prefix(const int* __restrict__ counts, int* __restrict__ offsets) {
    if (threadIdx.x == 0 && blockIdx.x == 0) {
        int acc = 0;
        for (int k = 0; k < NKPT; k++) { offsets[k] = acc; acc += counts[k]; }
        offsets[NKPT] = acc;
    }
}

// ---------------- fp32 GEMM: |feats·inv_f  @  pnT| -> proto_logits ----------------
__global__ __launch_bounds__(256) void k_gemm(const float* __restrict__ feats,
                                              const float* __restrict__ pn,
                                              const float* __restrict__ inv_f,
                                              float* __restrict__ out_logits) {
    __shared__ float As[KC][BR + 4];
    __shared__ float Bs[KC][BC + 4];
    int tid = threadIdx.x;
    int tx = tid & 15, ty = tid >> 4;
    int row0 = blockIdx.x * BR;
    float acc[8][12];
    #pragma unroll
    for (int i = 0; i < 8; i++)
        #pragma unroll
        for (int j = 0; j < 12; j++) acc[i][j] = 0.f;
    int lr = tid >> 3;            // 0..31
    int lk = (tid & 7) * 4;       // 0,4,..,28
    for (int kc = 0; kc < DD; kc += KC) {
        #pragma unroll
        for (int p = 0; p < 4; p++) {        // A: 128 rows x 32 k
            int r = lr + p * 32;
            float4 v = *(const float4*)(feats + (size_t)(row0 + r) * DD + kc + lk);
            As[lk + 0][r] = v.x; As[lk + 1][r] = v.y; As[lk + 2][r] = v.z; As[lk + 3][r] = v.w;
        }
        #pragma unroll
        for (int p = 0; p < 6; p++) {        // B: 192 cols x 32 k (pad cols >=170 with 0)
            int c = lr + p * 32;
            float4 v = make_float4(0.f, 0.f, 0.f, 0.f);
            if (c < CC) v = *(const float4*)(pn + (size_t)c * DD + kc + lk);
            Bs[lk + 0][c] = v.x; Bs[lk + 1][c] = v.y; Bs[lk + 2][c] = v.z; Bs[lk + 3][c] = v.w;
        }
        __syncthreads();
        #pragma unroll 4
        for (int k = 0; k < KC; k++) {
            float a[8], b[12];
            *(float4*)&a[0] = *(const float4*)&As[k][ty * 8];
            *(float4*)&a[4] = *(const float4*)&As[k][ty * 8 + 4];
            *(float4*)&b[0] = *(const float4*)&Bs[k][tx * 12];
            *(float4*)&b[4] = *(const float4*)&Bs[k][tx * 12 + 4];
            *(float4*)&b[8] = *(const float4*)&Bs[k][tx * 12 + 8];
            #pragma unroll
            for (int i = 0; i < 8; i++)
                #pragma unroll
                for (int j = 0; j < 12; j++)
                    acc[i][j] = fmaf(a[i], b[j], acc[i][j]);
        }
        __syncthreads();
    }
    #pragma unroll
    for (int i = 0; i < 8; i++) {
        int r = row0 + ty * 8 + i;
        float s = inv_f[r];
        #pragma unroll
        for (int j = 0; j < 12; j++) {
            int c = tx * 12 + j;
            if (c < CC) out_logits[(size_t)r * CC + c] = fabsf(acc[i][j] * s);
        }
    }
}

// ---------------- per-row epilogue: kpt_class, conf_eff, exp, class-sorted scatter --------
__global__ __launch_bounds__(256) void k_epilogue(const float* __restrict__ logits,
                                                  const int* __restrict__ gt,
                                                  const float* __restrict__ conf,
                                                  const float* __restrict__ inv_f,
                                                  const int* __restrict__ offsets,
                                                  int* __restrict__ cursor,
                                                  float* __restrict__ kpt_out,
                                                  double* __restrict__ Es,
                                                  int* __restrict__ perm,
                                                  float* __restrict__ wq_s,
                                                  float* __restrict__ wn_s) {
    __shared__ float S[EROWS][CC + 1];     // stride 171 (odd) -> 2-way banks, free
    __shared__ int cnt[NKPT];
    __shared__ int base[NKPT];
    int t = threadIdx.x;
    int row0 = blockIdx.x * EROWS;
    for (int idx = t; idx < EROWS * CC; idx += 256) {
        int r = idx / CC, c = idx - r * CC;
        S[r][c] = logits[(size_t)(row0 + r) * CC + c];
    }
    if (t < NKPT) cnt[t] = 0;
    __syncthreads();
    int cls = 0, lrank = 0;
    float wq = 0.f, wn = 0.f;
    double e[MM];
    bool active = (t < EROWS);
    if (active) {
        int n = row0 + t;
        float best = -1.f; int pred = 0;
        #pragma unroll
        for (int k = 0; k < NKPT; k++) {
            float mx = S[t][k * MM];
            #pragma unroll
            for (int m = 1; m < MM; m++) mx = fmaxf(mx, S[t][k * MM + m]);
            kpt_out[(size_t)n * NKPT + k] = fminf(fmaxf(mx, 1e-4f), 1.f - 1e-4f);
            if (mx > best) { best = mx; pred = k; }   // strict > : first-max, matches jnp.argmax
        }
        cls = gt[n];
        float ce = (pred == cls) ? conf[n] : 0.f;
        wq = ce * ce * inv_f[n];      // conf_eff^2 * (feats row scale)
        wn = ce;
        #pragma unroll
        for (int m = 0; m < MM; m++) e[m] = exp(20.0 * (double)S[t][cls * MM + m]);
        lrank = atomicAdd(&cnt[cls], 1);
    }
    __syncthreads();
    if (t < NKPT) base[t] = atomicAdd(&cursor[t], cnt[t]);
    __syncthreads();
    if (active) {
        int n = row0 + t;
        int pos = offsets[cls] + base[cls] + lrank;
        perm[pos] = n;
        wq_s[pos] = wq;
        wn_s[pos] = wn;
        #pragma unroll
        for (int m = 0; m < MM; m++) Es[(size_t)pos * MM + m] = e[m];
    }
}

// ---------------- Sinkhorn column-sum of a (fp64) ----------------
__global__ __launch_bounds__(256) void k_colsumA(const double* __restrict__ Es,
                                                 const int* __restrict__ offsets,
                                                 double* __restrict__ A) {
    int k  = blockIdx.x / CHUNKS;
    int ch = blockIdx.x % CHUNKS;
    int j0 = offsets[k], j1 = offsets[k + 1];
    long long len = j1 - j0;
    int c0 = j0 + (int)(len * ch / CHUNKS);
    int c1 = j0 + (int)(len * (ch + 1) / CHUNKS);
    int t = threadIdx.x;
    double acc[MM];
    #pragma unroll
    for (int m = 0; m < MM; m++) acc[m] = 0.0;
    for (int j = c0 + t; j < c1; j += 256) {
        #pragma unroll
        for (int m = 0; m < MM; m++) acc[m] += Es[(size_t)j * MM + m];
    }
    __shared__ double red[4][MM];
    int lane = t & 63, w = t >> 6;
    #pragma unroll
    for (int m = 0; m < MM; m++) {
        double v = acc[m];
        for (int off = 32; off > 0; off >>= 1) v += __shfl_down(v, off);
        if (lane == 0) red[w][m] = v;
    }
    __syncthreads();
    if (t < MM) atomicAdd(&A[k * MM + t], red[0][t] + red[1][t] + red[2][t] + red[3][t]);
}

// ---------------- one Sinkhorn iteration: T_m = sum_n a*rowf,  rowf = 1/(B*sum_m a*colf) ---
__global__ __launch_bounds__(256) void k_iter(const double* __restrict__ Es,
                                              const int* __restrict__ offsets,
                                              const int* __restrict__ counts,
                                              const double* __restrict__ colf,
                                              double* __restrict__ T) {
    int k  = blockIdx.x / CHUNKS;
    int ch = blockIdx.x % CHUNKS;
    int j0 = offsets[k], j1 = offsets[k + 1];
    long long len = j1 - j0;
    int c0 = j0 + (int)(len * ch / CHUNKS);
    int c1 = j0 + (int)(len * (ch + 1) / CHUNKS);
    int t = threadIdx.x;
    double cf[MM];
    #pragma unroll
    for (int m = 0; m < MM; m++) cf[m] = colf[k * MM + m];
    double Bk = (double)counts[k];
    double acc[MM];
    #pragma unroll
    for (int m = 0; m < MM; m++) acc[m] = 0.0;
    for (int j = c0 + t; j < c1; j += 256) {
        double e[MM], rs = 0.0;
        #pragma unroll
        for (int m = 0; m < MM; m++) { e[m] = Es[(size_t)j * MM + m]; rs += e[m] * cf[m]; }
        double rowf = 1.0 / (Bk * rs);
        #pragma unroll
        for (int m = 0; m < MM; m++) acc[m] += e[m] * rowf;
    }
    __shared__ double red[4][MM];
    int lane = t & 63, w = t >> 6;
    #pragma unroll
    for (int m = 0; m < MM; m++) {
        double v = acc[m];
        for (int off = 32; off > 0; off >>= 1) v += __shfl_down(v, off);
        if (lane == 0) red[w][m] = v;
    }
    __syncthreads();
    if (t < MM) atomicAdd(&T[k * MM + t], red[0][t] + red[1][t] + red[2][t] + red[3][t]);
}

// colf1 = S/(10*A)  (initial global normalization folds into S)
__global__ __launch_bounds__(256) void k_colf1(const double* __restrict__ A,
                                               double* __restrict__ colf) {
    int t = threadIdx.x;
    __shared__ double red[256];
    red[t] = (t < CC) ? A[t] : 0.0;
    __syncthreads();
    for (int s = 128; s > 0; s >>= 1) { if (t < s) red[t] += red[t + s]; __syncthreads(); }
    if (t < CC) colf[t] = red[0] / (10.0 * A[t]);
}

// colf = 1/(10*T)
__global__ __launch_bounds__(256) void k_colf(const double* __restrict__ T,
                                              double* __restrict__ colf) {
    int t = threadIdx.x;
    if (t < CC) colf[t] = 1.0 / (10.0 * T[t]);
}

// ---------------- final argmax (row factors cancel) -> proto_target, assign ----------------
__global__ __launch_bounds__(256) void k_argmax(const double* __restrict__ Es,
                                                const int* __restrict__ offsets,
                                                const double* __restrict__ colf3,
                                                const int* __restrict__ perm,
                                                float* __restrict__ o1,
                                                int* __restrict__ assign) {
    int k  = blockIdx.x / CHUNKS;
    int ch = blockIdx.x % CHUNKS;
    int j0 = offsets[k], j1 = offsets[k + 1];
    long long len = j1 - j0;
    int c0 = j0 + (int)(len * ch / CHUNKS);
    int c1 = j0 + (int)(len * (ch + 1) / CHUNKS);
    int t = threadIdx.x;
    double cf[MM];
    #pragma unroll
    for (int m = 0; m < MM; m++) cf[m] = colf3[k * MM + m];
    for (int j = c0 + t; j < c1; j += 256) {
        double bestv = Es[(size_t)j * MM] * cf[0];
        int bi = 0;
        #pragma unroll
        for (int m = 1; m < MM; m++) {
            double v = Es[(size_t)j * MM + m] * cf[m];
            if (v > bestv) { bestv = v; bi = m; }
        }
        o1[perm[j]] = (float)(bi + MM * k);
        assign[j] = bi;
    }
}

// ---------------- weighted gather of feats into f_raw[k,m,:], n_km ----------------
__global__ __launch_bounds__(256) void k_gather(const float* __restrict__ feats,
                                                const int* __restrict__ offsets,
                                                const int* __restrict__ perm,
                                                const int* __restrict__ assign,
                                                const float* __restrict__ wq_s,
                                                const float* __restrict__ wn_s,
                                                float* __restrict__ f_raw,
                                                float* __restrict__ nkm) {
    int c = blockIdx.x;            // 0..169
    int k = c / MM, m = c - k * MM;
    int ch = blockIdx.y;
    int j0 = offsets[k], j1 = offsets[k + 1];
    long long len = j1 - j0;
    int c0 = j0 + (int)(len * ch / GCH);
    int c1 = j0 + (int)(len * (ch + 1) / GCH);
    int t = threadIdx.x;
    float a0 = 0.f, a1 = 0.f, a2 = 0.f, nacc = 0.f;
    __shared__ int   als[256];
    __shared__ float wls[256];
    __shared__ int   rls[256];
    __shared__ float nls[256];
    for (int jb = c0; jb < c1; jb += 256) {
        int j = jb + t;
        if (j < c1) { als[t] = assign[j]; wls[t] = wq_s[j]; rls[t] = perm[j]; nls[t] = wn_s[j]; }
        __syncthreads();
        int lim = min(256, c1 - jb);
        for (int i = 0; i < lim; i++) {
            if (als[i] == m && wls[i] != 0.f) {     // zero conf_eff rows contribute 0
                float w = wls[i];
                const float* row = feats + (size_t)rls[i] * DD;
                a0 = fmaf(w, row[t], a0);
                a1 = fmaf(w, row[t + 256], a1);
                a2 = fmaf(w, row[t + 512], a2);
                if (t == 0) nacc += nls[i];
            }
        }
        __syncthreads();
    }
    atomicAdd(&f_raw[(size_t)c * DD + t], a0);
    atomicAdd(&f_raw[(size_t)c * DD + t + 256], a1);
    atomicAdd(&f_raw[(size_t)c * DD + t + 512], a2);
    if (t == 0) atomicAdd(&nkm[c], nacc);
}

// ---------------- new_protos epilogue ----------------
__global__ __launch_bounds__(256) void k_newproto(const float* __restrict__ f_raw,
                                                  const float* __restrict__ nkm,
                                                  const float* __restrict__ pn,
                                                  float* __restrict__ o3) {
    int c = blockIdx.x, t = threadIdx.x;
    int k = c / MM;
    float f0 = f_raw[(size_t)c * DD + t];
    float f1 = f_raw[(size_t)c * DD + t + 256];
    float f2 = f_raw[(size_t)c * DD + t + 512];
    __shared__ double red[256];
    red[t] = (double)f0 * f0 + (double)f1 * f1 + (double)f2 * f2;
    __syncthreads();
    for (int s = 128; s > 0; s >>= 1) { if (t < s) red[t] += red[t + s]; __syncthreads(); }
    float invf = (float)(1.0 / fmax(sqrt(red[0]), 1e-12));
    bool valid = (nkm[c] != 0.f);
    float hs = 0.f;
    #pragma unroll
    for (int m = 0; m < MM; m++) hs += nkm[k * MM + m];
    bool has = (hs > 0.f);
    float p0 = pn[(size_t)c * DD + t];
    float p1 = pn[(size_t)c * DD + t + 256];
    float p2 = pn[(size_t)c * DD + t + 512];
    float v0, v1, v2;
    if (has && valid) {
        v0 = 0.999f * p0 + 0.001f * (f0 * invf);
        v1 = 0.999f * p1 + 0.001f * (f1 * invf);
        v2 = 0.999f * p2 + 0.001f * (f2 * invf);
    } else { v0 = p0; v1 = p1; v2 = p2; }
    __syncthreads();                       // red[0] consumed by all before reuse
    red[t] = (double)v0 * v0 + (double)v1 * v1 + (double)v2 * v2;
    __syncthreads();
    for (int s = 128; s > 0; s >>= 1) { if (t < s) red[t] += red[t + s]; __syncthreads(); }
    float inv2 = (float)(1.0 / fmax(sqrt(red[0]), 1e-12));
    o3[(size_t)c * DD + t]       = v0 * inv2;
    o3[(size_t)c * DD + t + 256] = v1 * inv2;
    o3[(size_t)c * DD + t + 512] = v2 * inv2;
}

extern "C" void kernel_launch(void* const* d_in, const int* in_sizes, int n_in,
                              void* d_out, int out_size, void* d_ws, size_t ws_size,
                              hipStream_t stream) {
    const float* feats  = (const float*)d_in[0];
    const int*   gt     = (const int*)d_in[1];
    const float* conf   = (const float*)d_in[2];
    const float* protos = (const float*)d_in[3];

    float* o0 = (float*)d_out;                       // proto_logits  N x 170
    float* o1 = o0 + (size_t)NN * CC;                // proto_target  N
    float* o2 = o1 + NN;                             // kpt_class     N x 17
    float* o3 = o2 + (size_t)NN * NKPT;              // new_protos    170 x 768

    char* ws = (char*)d_ws;
    float*  inv_f  = (float*)(ws + 0);               // N f32
    float*  pn     = (float*)(ws + 524288);          // 170x768 f32
    float*  wq_s   = (float*)(ws + 1048576);         // N f32 (sorted)
    float*  wn_s   = (float*)(ws + 1572864);         // N f32 (sorted)
    int*    perm   = (int*)  (ws + 2097152);         // N i32
    int*    assign = (int*)  (ws + 2621440);         // N i32
    double* Es     = (double*)(ws + 3145728);        // N x 10 f64
    char*   zz     = ws + 13631488;                  // zero zone start
    int*    counts = (int*)  (zz + 0);
    int*    cursor = (int*)  (zz + 128);
    int*    offs   = (int*)  (zz + 256);
    double* A      = (double*)(zz + 384);
    double* T1     = (double*)(zz + 384 + 2048);
    double* T2     = (double*)(zz + 384 + 4096);
    double* colf1  = (double*)(zz + 384 + 6144);
    double* colf2  = (double*)(zz + 384 + 8192);
    double* colf3  = (double*)(zz + 384 + 10240);
    float*  nkm    = (float*) (zz + 384 + 12288);
    float*  f_raw  = (float*) (zz + 384 + 12288 + 1024);
    size_t  zz_bytes = 384 + 12288 + 1024 + (size_t)CC * DD * 4;

    hipMemsetAsync(zz, 0, zz_bytes, stream);
    k_proto_norm<<<CC, 256, 0, stream>>>(protos, pn);
    k_feat_norm<<<NN, 64, 0, stream>>>(feats, inv_f);
    k_hist<<<512, 256, 0, stream>>>(gt, counts);
    k_prefix<<<1, 64, 0, stream>>>(counts, offs);
    k_gemm<<<NN / BR, 256, 0, stream>>>(feats, pn, inv_f, o0);
    k_epilogue<<<NN / EROWS, 256, 0, stream>>>(o0, gt, conf, inv_f, offs, cursor,
                                               o2, Es, perm, wq_s, wn_s);
    k_colsumA<<<NKPT * CHUNKS, 256, 0, stream>>>(Es, offs, A);
    k_colf1<<<1, 256, 0, stream>>>(A, colf1);
    k_iter<<<NKPT * CHUNKS, 256, 0, stream>>>(Es, offs, counts, colf1, T1);
    k_colf<<<1, 256, 0, stream>>>(T1, colf2);
    k_iter<<<NKPT * CHUNKS, 256, 0, stream>>>(Es, offs, counts, colf2, T2);
    k_colf<<<1, 256, 0, stream>>>(T2, colf3);
    k_argmax<<<NKPT * CHUNKS, 256, 0, stream>>>(Es, offs, colf3, perm, o1, assign);
    dim3 gg(CC, GCH);
    k_gather<<<gg, 256, 0, stream>>>(feats, offs, perm, assign, wq_s, wn_s, f_raw, nkm);
    k_newproto<<<CC, 256, 0, stream>>>(f_raw, nkm, pn, o3);
}

// Round 2
// 844.159 us; speedup vs baseline: 1.3393x; 1.3393x over previous
//
#include <hip/hip_runtime.h>
#include <math.h>

#define NKPT 17
#define MM   10
#define DD   768
#define NN   131072
#define CC   (NKPT*MM)   // 170
#define CHUNKS 16
#define GCH    8

typedef __bf16 bf16_t;
typedef bf16_t bf16x8 __attribute__((ext_vector_type(8)));
typedef float  f32x16 __attribute__((ext_vector_type(16)));

#define GLOAD_LDS16(g, s) \
    __builtin_amdgcn_global_load_lds((const __attribute__((address_space(1))) void*)(g), \
                                     (__attribute__((address_space(3))) void*)(s), 16, 0, 0)

// ---------------- proto norms: pn (fp32 normalized) + pnb (bf16, 192 rows, pad=0) ---------
__global__ __launch_bounds__(256) void k_proto_norm(const float* __restrict__ protos,
                                                    float* __restrict__ pn,
                                                    bf16_t* __restrict__ pnb) {
    int c = blockIdx.x;           // 0..191
    int t = threadIdx.x;          // 256
    if (c >= CC) {                // zero padding rows for the GEMM B-tile
        pnb[(size_t)c * DD + t]       = (bf16_t)0.f;
        pnb[(size_t)c * DD + t + 256] = (bf16_t)0.f;
        pnb[(size_t)c * DD + t + 512] = (bf16_t)0.f;
        return;
    }
    const float* row = protos + (size_t)c * DD;
    float v0 = row[t], v1 = row[t + 256], v2 = row[t + 512];
    double ss = (double)v0 * v0 + (double)v1 * v1 + (double)v2 * v2;
    __shared__ double red[256];
    red[t] = ss; __syncthreads();
    for (int s = 128; s > 0; s >>= 1) { if (t < s) red[t] += red[t + s]; __syncthreads(); }
    float invf = (float)(1.0 / fmax(sqrt(red[0]), 1e-12));
    float a0 = v0 * invf, a1 = v1 * invf, a2 = v2 * invf;
    pn[(size_t)c * DD + t]        = a0;
    pn[(size_t)c * DD + t + 256]  = a1;
    pn[(size_t)c * DD + t + 512]  = a2;
    pnb[(size_t)c * DD + t]       = (bf16_t)a0;
    pnb[(size_t)c * DD + t + 256] = (bf16_t)a1;
    pnb[(size_t)c * DD + t + 512] = (bf16_t)a2;
}

// ---------------- class histogram ----------------
__global__ __launch_bounds__(256) void k_hist(const int* __restrict__ gt,
                                              int* __restrict__ counts) {
    __shared__ int c[NKPT];
    int t = threadIdx.x;
    if (t < NKPT) c[t] = 0;
    __syncthreads();
    for (int i = blockIdx.x * blockDim.x + t; i < NN; i += gridDim.x * blockDim.x)
        atomicAdd(&c[gt[i]], 1);
    __syncthreads();
    if (t < NKPT) atomicAdd(&counts[t], c[t]);
}

__global__ void k_prefix(const int* __restrict__ counts, int* __restrict__ offsets) {
    if (threadIdx.x == 0 && blockIdx.x == 0) {
        int acc = 0;
        for (int k = 0; k < NKPT; k++) { offsets[k] = acc; acc += counts[k]; }
        offsets[NKPT] = acc;
    }
}

// ---------------- class-sort: perm (pos->row), rank (row->pos) ----------------
__global__ __launch_bounds__(256) void k_rank(const int* __restrict__ gt,
                                              const int* __restrict__ offs,
                                              int* __restrict__ cursor,
                                              int* __restrict__ perm,
                                              int* __restrict__ rank) {
    __shared__ int cnt[NKPT], base[NKPT];
    int t = threadIdx.x;
    if (t < NKPT) cnt[t] = 0;
    __syncthreads();
    int n = blockIdx.x * 256 + t;
    int cls = gt[n];
    int lr = atomicAdd(&cnt[cls], 1);
    __syncthreads();
    if (t < NKPT) base[t] = atomicAdd(&cursor[t], cnt[t]);
    __syncthreads();
    int p = offs[cls] + base[cls] + lr;
    perm[p] = n;
    rank[n] = p;
}

// ---------------- fused: feat norms + precise fp32 gt-class dots -> Es ----------------
// block = 256 thr = 4 waves; 32 class-sorted rows/block; 4 rows per wave-group.
__global__ __launch_bounds__(256) void k_prep(const float* __restrict__ feats,
                                              const float* __restrict__ pn,
                                              const int* __restrict__ gt,
                                              const int* __restrict__ perm,
                                              float* __restrict__ inv_f,
                                              double* __restrict__ Es) {
    __shared__ float pnS[MM * DD];    // 30 KB: the block's class prototypes
    int t = threadIdx.x, w = t >> 6, l = t & 63;
    int p0 = blockIdx.x * 32;
    int c0 = gt[perm[p0]];
    for (int idx = t; idx < MM * DD; idx += 256) pnS[idx] = pn[(size_t)c0 * DD * MM / MM * 0 + (size_t)c0 * MM * DD / (MM * DD) * 0 + (size_t)c0 * (MM * DD) + idx];
    __syncthreads();
    for (int g = 0; g < 2; g++) {
        int pg = p0 + w * 8 + g * 4;
        int nr[4], cl[4];
        bool uni = true;
        #pragma unroll
        for (int rr = 0; rr < 4; rr++) {
            nr[rr] = perm[pg + rr];
            cl[rr] = gt[nr[rr]];
            if (cl[rr] != c0) uni = false;
        }
        float4 fA[4][3];
        #pragma unroll
        for (int rr = 0; rr < 4; rr++) {
            const float4* r4 = (const float4*)(feats + (size_t)nr[rr] * DD);
            fA[rr][0] = r4[l]; fA[rr][1] = r4[l + 64]; fA[rr][2] = r4[l + 128];
        }
        // norms (fp64, butterfly)
        double ss[4];
        #pragma unroll
        for (int rr = 0; rr < 4; rr++) {
            float4 a = fA[rr][0], b = fA[rr][1], c = fA[rr][2];
            ss[rr] = (double)a.x*a.x + (double)a.y*a.y + (double)a.z*a.z + (double)a.w*a.w
                   + (double)b.x*b.x + (double)b.y*b.y + (double)b.z*b.z + (double)b.w*b.w
                   + (double)c.x*c.x + (double)c.y*c.y + (double)c.z*c.z + (double)c.w*c.w;
        }
        #pragma unroll
        for (int st = 1; st < 64; st <<= 1)
            #pragma unroll
            for (int rr = 0; rr < 4; rr++) ss[rr] += __shfl_xor(ss[rr], st);
        float inv[4];
        #pragma unroll
        for (int rr = 0; rr < 4; rr++) inv[rr] = (float)(1.0 / fmax(sqrt(ss[rr]), 1e-12));
        if (l == 0) {
            #pragma unroll
            for (int rr = 0; rr < 4; rr++) inv_f[nr[rr]] = inv[rr];
        }
        // 10 precise dots per row (fp32 partials + butterfly)
        float part[MM][4];
        if (uni) {
            #pragma unroll
            for (int m = 0; m < MM; m++) {
                const float4* P = (const float4*)(pnS + m * DD);
                float4 b0 = P[l], b1 = P[l + 64], b2 = P[l + 128];
                #pragma unroll
                for (int rr = 0; rr < 4; rr++) {
                    float4 a0 = fA[rr][0], a1 = fA[rr][1], a2 = fA[rr][2];
                    float v = a0.x*b0.x + a0.y*b0.y + a0.z*b0.z + a0.w*b0.w;
                    v = fmaf(a1.x, b1.x, v); v = fmaf(a1.y, b1.y, v);
                    v = fmaf(a1.z, b1.z, v); v = fmaf(a1.w, b1.w, v);
                    v = fmaf(a2.x, b2.x, v); v = fmaf(a2.y, b2.y, v);
                    v = fmaf(a2.z, b2.z, v); v = fmaf(a2.w, b2.w, v);
                    part[m][rr] = v;
                }
            }
        } else {
            #pragma unroll
            for (int m = 0; m < MM; m++) {
                #pragma unroll
                for (int rr = 0; rr < 4; rr++) {
                    const float4* P = (const float4*)(pn + (size_t)cl[rr] * (MM * DD) + m * DD);
                    float4 b0 = P[l], b1 = P[l + 64], b2 = P[l + 128];
                    float4 a0 = fA[rr][0], a1 = fA[rr][1], a2 = fA[rr][2];
                    float v = a0.x*b0.x + a0.y*b0.y + a0.z*b0.z + a0.w*b0.w;
                    v = fmaf(a1.x, b1.x, v); v = fmaf(a1.y, b1.y, v);
                    v = fmaf(a1.z, b1.z, v); v = fmaf(a1.w, b1.w, v);
                    v = fmaf(a2.x, b2.x, v); v = fmaf(a2.y, b2.y, v);
                    v = fmaf(a2.z, b2.z, v); v = fmaf(a2.w, b2.w, v);
                    part[m][rr] = v;
                }
            }
        }
        #pragma unroll
        for (int st = 1; st < 64; st <<= 1)
            #pragma unroll
            for (int m = 0; m < MM; m++)
                #pragma unroll
                for (int rr = 0; rr < 4; rr++) part[m][rr] += __shfl_xor(part[m][rr], st);
        if (l < MM) {
            #pragma unroll
            for (int rr = 0; rr < 4; rr++) {
                float v = part[0][rr];
                #pragma unroll
                for (int m = 1; m < MM; m++) v = (l == m) ? part[m][rr] : v;
                float sf = fabsf(v * inv[rr]);
                Es[(size_t)(pg + rr) * MM + l] = exp(20.0 * (double)sf);
            }
        }
    }
}

// ---------------- bf16 MFMA GEMM: |(feats @ pnb^T) * inv_f| -> o0[N x 170] ----------------
// block 256 thr = 4 waves; tile 128 rows x 192 cols; BK = 64.
__global__ __launch_bounds__(256, 2) void k_gemm(const float* __restrict__ feats,
                                                 const bf16_t* __restrict__ pnb,
                                                 const float* __restrict__ inv_f,
                                                 float* __restrict__ o0) {
    __shared__ float  AsF[128 * 64];     // 32 KB fp32, 16B-chunk swizzled by (row&15)
    __shared__ bf16_t Bs[192 * 64];      // 24 KB bf16, 16B-chunk swizzled by (row&7)
    __shared__ float  sInv[128];
    int tid = threadIdx.x;
    int w = tid >> 6, l = tid & 63;
    int row0 = blockIdx.x * 128;
    if (tid < 128) sInv[tid] = inv_f[row0 + tid];
    f32x16 acc[6];
    #pragma unroll
    for (int ct = 0; ct < 6; ct++)
        #pragma unroll
        for (int i = 0; i < 16; i++) acc[ct][i] = 0.f;
    char* AsB = (char*)AsF;
    char* BsB = (char*)Bs;
    int am = l & 31, q = l >> 5;
    for (int kc = 0; kc < DD; kc += 64) {
        // A: 32 KB, 8 insts/wave, 4 rows per inst
        #pragma unroll
        for (int rep = 0; rep < 8; rep++) {
            int rg = w * 8 + rep;             // 0..31
            int r  = rg * 4 + (l >> 4);
            int cg = (l & 15) ^ (r & 15);
            const float* gp = feats + (size_t)(row0 + r) * DD + kc + cg * 4;
            GLOAD_LDS16(gp, AsB + rg * 1024);
        }
        // B: 24 KB, 6 insts/wave, 8 rows per inst
        #pragma unroll
        for (int rep = 0; rep < 6; rep++) {
            int rg = w * 6 + rep;             // 0..23
            int r  = rg * 8 + (l >> 3);
            int cg = (l & 7) ^ (r & 7);
            const bf16_t* gp = pnb + (size_t)r * DD + kc + cg * 8;
            GLOAD_LDS16(gp, BsB + rg * 1024);
        }
        __syncthreads();
        #pragma unroll
        for (int ks = 0; ks < 4; ks++) {
            int ar  = w * 32 + am;
            int c0a = ks * 4 + q * 2;
            int ca0 = (c0a)     ^ (ar & 15);
            int ca1 = (c0a + 1) ^ (ar & 15);
            float4 a0 = *(const float4*)(AsB + ar * 256 + ca0 * 16);
            float4 a1 = *(const float4*)(AsB + ar * 256 + ca1 * 16);
            bf16x8 af;
            af[0] = (bf16_t)a0.x; af[1] = (bf16_t)a0.y; af[2] = (bf16_t)a0.z; af[3] = (bf16_t)a0.w;
            af[4] = (bf16_t)a1.x; af[5] = (bf16_t)a1.y; af[6] = (bf16_t)a1.z; af[7] = (bf16_t)a1.w;
            #pragma unroll
            for (int ct = 0; ct < 6; ct++) {
                int br = ct * 32 + am;
                int cb = (ks * 2 + q) ^ (br & 7);
                bf16x8 bf = *(const bf16x8*)(BsB + br * 128 + cb * 16);
                acc[ct] = __builtin_amdgcn_mfma_f32_32x32x16_bf16(af, bf, acc[ct], 0, 0, 0);
            }
        }
        __syncthreads();
    }
    // epilogue: D[row][col]: col = ct*32 + (lane&31); row = (reg&3) + 8*(reg>>2) + 4*(lane>>5)
    #pragma unroll
    for (int ct = 0; ct < 6; ct++) {
        int col = ct * 32 + am;
        if (col < CC) {
            #pragma unroll
            for (int reg = 0; reg < 16; reg++) {
                int rl = w * 32 + (reg & 3) + 8 * (reg >> 2) + 4 * q;
                o0[(size_t)(row0 + rl) * CC + col] = fabsf(acc[ct][reg] * sInv[rl]);
            }
        }
    }
}

// ---------------- per-row epilogue from o0: kpt_class, pred, conf_eff ----------------
__global__ __launch_bounds__(256) void k_epi2(const float* __restrict__ o0,
                                              const int* __restrict__ gt,
                                              const float* __restrict__ conf,
                                              const float* __restrict__ inv_f,
                                              const int* __restrict__ rank,
                                              float* __restrict__ o2,
                                              float* __restrict__ wq_s,
                                              float* __restrict__ wn_s) {
    __shared__ float S[64][CC + 1];
    int t = threadIdx.x;
    int row0 = blockIdx.x * 64;
    for (int idx = t; idx < 64 * CC; idx += 256) {
        int r = idx / CC, c = idx - r * CC;
        S[r][c] = o0[(size_t)(row0 + r) * CC + c];
    }
    __syncthreads();
    if (t < 64) {
        int n = row0 + t;
        float best = -1.f; int pred = 0;
        #pragma unroll
        for (int k = 0; k < NKPT; k++) {
            float mx = S[t][k * MM];
            #pragma unroll
            for (int m = 1; m < MM; m++) mx = fmaxf(mx, S[t][k * MM + m]);
            o2[(size_t)n * NKPT + k] = fminf(fmaxf(mx, 1e-4f), 1.f - 1e-4f);
            if (mx > best) { best = mx; pred = k; }
        }
        int cls = gt[n];
        float ce = (pred == cls) ? conf[n] : 0.f;
        int pos = rank[n];
        wq_s[pos] = ce * ce * inv_f[n];
        wn_s[pos] = ce;
    }
}

// ---------------- Sinkhorn column-sum of a (fp64) ----------------
__global__ __launch_bounds__(256) void k_colsumA(const double* __restrict__ Es,
                                                 const int* __restrict__ offsets,
                                                 double* __restrict__ A) {
    int k  = blockIdx.x / CHUNKS;
    int ch = blockIdx.x % CHUNKS;
    int j0 = offsets[k], j1 = offsets[k + 1];
    long long len = j1 - j0;
    int c0 = j0 + (int)(len * ch / CHUNKS);
    int c1 = j0 + (int)(len * (ch + 1) / CHUNKS);
    int t = threadIdx.x;
    double acc[MM];
    #pragma unroll
    for (int m = 0; m < MM; m++) acc[m] = 0.0;
    for (int j = c0 + t; j < c1; j += 256) {
        #pragma unroll
        for (int m = 0; m < MM; m++) acc[m] += Es[(size_t)j * MM + m];
    }
    __shared__ double red[4][MM];
    int lane = t & 63, w = t >> 6;
    #pragma unroll
    for (int m = 0; m < MM; m++) {
        double v = acc[m];
        for (int off = 32; off > 0; off >>= 1) v += __shfl_down(v, off);
        if (lane == 0) red[w][m] = v;
    }
    __syncthreads();
    if (t < MM) atomicAdd(&A[k * MM + t], red[0][t] + red[1][t] + red[2][t] + red[3][t]);
}

// ---------------- one Sinkhorn iteration ----------------
__global__ __launch_bounds__(256) void k_iter(const double* __restrict__ Es,
                                              const int* __restrict__ offsets,
                                              const int* __restrict__ counts,
                                              const double* __restrict__ colf,
                                              double* __restrict__ T) {
    int k  = blockIdx.x / CHUNKS;
    int ch = blockIdx.x % CHUNKS;
    int j0 = offsets[k], j1 = offsets[k + 1];
    long long len = j1 - j0;
    int c0 = j0 + (int)(len * ch / CHUNKS);
    int c1 = j0 + (int)(len * (ch + 1) / CHUNKS);
    int t = threadIdx.x;
    double cf[MM];
    #pragma unroll
    for (int m = 0; m < MM; m++) cf[m] = colf[k * MM + m];
    double Bk = (double)counts[k];
    double acc[MM];
    #pragma unroll
    for (int m = 0; m < MM; m++) acc[m] = 0.0;
    for (int j = c0 + t; j < c1; j += 256) {
        double e[MM], rs = 0.0;
        #pragma unroll
        for (int m = 0; m < MM; m++) { e[m] = Es[(size_t)j * MM + m]; rs += e[m] * cf[m]; }
        double rowf = 1.0 / (Bk * rs);
        #pragma unroll
        for (int m = 0; m < MM; m++) acc[m] += e[m] * rowf;
    }
    __shared__ double red[4][MM];
    int lane = t & 63, w = t >> 6;
    #pragma unroll
    for (int m = 0; m < MM; m++) {
        double v = acc[m];
        for (int off = 32; off > 0; off >>= 1) v += __shfl_down(v, off);
        if (lane == 0) red[w][m] = v;
    }
    __syncthreads();
    if (t < MM) atomicAdd(&T[k * MM + t], red[0][t] + red[1][t] + red[2][t] + red[3][t]);
}

__global__ __launch_bounds__(256) void k_colf1(const double* __restrict__ A,
                                               double* __restrict__ colf) {
    int t = threadIdx.x;
    __shared__ double red[256];
    red[t] = (t < CC) ? A[t] : 0.0;
    __syncthreads();
    for (int s = 128; s > 0; s >>= 1) { if (t < s) red[t] += red[t + s]; __syncthreads(); }
    if (t < CC) colf[t] = red[0] / (10.0 * A[t]);
}

__global__ __launch_bounds__(256) void k_colf(const double* __restrict__ T,
                                              double* __restrict__ colf) {
    int t = threadIdx.x;
    if (t < CC) colf[t] = 1.0 / (10.0 * T[t]);
}

// ---------------- final argmax -> proto_target, assign ----------------
__global__ __launch_bounds__(256) void k_argmax(const double* __restrict__ Es,
                                                const int* __restrict__ offsets,
                                                const double* __restrict__ colf3,
                                                const int* __restrict__ perm,
                                                float* __restrict__ o1,
                                                int* __restrict__ assign) {
    int k  = blockIdx.x / CHUNKS;
    int ch = blockIdx.x % CHUNKS;
    int j0 = offsets[k], j1 = offsets[k + 1];
    long long len = j1 - j0;
    int c0 = j0 + (int)(len * ch / CHUNKS);
    int c1 = j0 + (int)(len * (ch + 1) / CHUNKS);
    int t = threadIdx.x;
    double cf[MM];
    #pragma unroll
    for (int m = 0; m < MM; m++) cf[m] = colf3[k * MM + m];
    for (int j = c0 + t; j < c1; j += 256) {
        double bestv = Es[(size_t)j * MM] * cf[0];
        int bi = 0;
        #pragma unroll
        for (int m = 1; m < MM; m++) {
            double v = Es[(size_t)j * MM + m] * cf[m];
            if (v > bestv) { bestv = v; bi = m; }
        }
        o1[perm[j]] = (float)(bi + MM * k);
        assign[j] = bi;
    }
}

// ---------------- weighted gather of feats into f_raw[k,m,:], n_km ----------------
__global__ __launch_bounds__(256) void k_gather(const float* __restrict__ feats,
                                                const int* __restrict__ offsets,
                                                const int* __restrict__ perm,
                                                const int* __restrict__ assign,
                                                const float* __restrict__ wq_s,
                                                const float* __restrict__ wn_s,
                                                float* __restrict__ f_raw,
                                                float* __restrict__ nkm) {
    int c = blockIdx.x;            // 0..169
    int k = c / MM, m = c - k * MM;
    int ch = blockIdx.y;
    int j0 = offsets[k], j1 = offsets[k + 1];
    long long len = j1 - j0;
    int c0 = j0 + (int)(len * ch / GCH);
    int c1 = j0 + (int)(len * (ch + 1) / GCH);
    int t = threadIdx.x;
    float a0 = 0.f, a1 = 0.f, a2 = 0.f, nacc = 0.f;
    __shared__ int   als[256];
    __shared__ float wls[256];
    __shared__ int   rls[256];
    __shared__ float nls[256];
    for (int jb = c0; jb < c1; jb += 256) {
        int j = jb + t;
        if (j < c1) { als[t] = assign[j]; wls[t] = wq_s[j]; rls[t] = perm[j]; nls[t] = wn_s[j]; }
        __syncthreads();
        int lim = min(256, c1 - jb);
        for (int i = 0; i < lim; i++) {
            if (als[i] == m && wls[i] != 0.f) {
                float w = wls[i];
                const float* row = feats + (size_t)rls[i] * DD;
                a0 = fmaf(w, row[t], a0);
                a1 = fmaf(w, row[t + 256], a1);
                a2 = fmaf(w, row[t + 512], a2);
                if (t == 0) nacc += nls[i];
            }
        }
        __syncthreads();
    }
    atomicAdd(&f_raw[(size_t)c * DD + t], a0);
    atomicAdd(&f_raw[(size_t)c * DD + t + 256], a1);
    atomicAdd(&f_raw[(size_t)c * DD + t + 512], a2);
    if (t == 0) atomicAdd(&nkm[c], nacc);
}

// ---------------- new_protos epilogue ----------------
__global__ __launch_bounds__(256) void k_newproto(const float* __restrict__ f_raw,
                                                  const float* __restrict__ nkm,
                                                  const float* __restrict__ pn,
                                                  float* __restrict__ o3) {
    int c = blockIdx.x, t = threadIdx.x;
    int k = c / MM;
    float f0 = f_raw[(size_t)c * DD + t];
    float f1 = f_raw[(size_t)c * DD + t + 256];
    float f2 = f_raw[(size_t)c * DD + t + 512];
    __shared__ double red[256];
    red[t] = (double)f0 * f0 + (double)f1 * f1 + (double)f2 * f2;
    __syncthreads();
    for (int s = 128; s > 0; s >>= 1) { if (t < s) red[t] += red[t + s]; __syncthreads(); }
    float invf = (float)(1.0 / fmax(sqrt(red[0]), 1e-12));
    bool valid = (nkm[c] != 0.f);
    float hs = 0.f;
    #pragma unroll
    for (int m = 0; m < MM; m++) hs += nkm[k * MM + m];
    bool has = (hs > 0.f);
    float p0 = pn[(size_t)c * DD + t];
    float p1 = pn[(size_t)c * DD + t + 256];
    float p2 = pn[(size_t)c * DD + t + 512];
    float v0, v1, v2;
    if (has && valid) {
        v0 = 0.999f * p0 + 0.001f * (f0 * invf);
        v1 = 0.999f * p1 + 0.001f * (f1 * invf);
        v2 = 0.999f * p2 + 0.001f * (f2 * invf);
    } else { v0 = p0; v1 = p1; v2 = p2; }
    __syncthreads();
    red[t] = (double)v0 * v0 + (double)v1 * v1 + (double)v2 * v2;
    __syncthreads();
    for (int s = 128; s > 0; s >>= 1) { if (t < s) red[t] += red[t + s]; __syncthreads(); }
    float inv2 = (float)(1.0 / fmax(sqrt(red[0]), 1e-12));
    o3[(size_t)c * DD + t]       = v0 * inv2;
    o3[(size_t)c * DD + t + 256] = v1 * inv2;
    o3[(size_t)c * DD + t + 512] = v2 * inv2;
}

extern "C" void kernel_launch(void* const* d_in, const int* in_sizes, int n_in,
                              void* d_out, int out_size, void* d_ws, size_t ws_size,
                              hipStream_t stream) {
    const float* feats  = (const float*)d_in[0];
    const int*   gt     = (const int*)d_in[1];
    const float* conf   = (const float*)d_in[2];
    const float* protos = (const float*)d_in[3];

    float* o0 = (float*)d_out;                       // proto_logits  N x 170
    float* o1 = o0 + (size_t)NN * CC;                // proto_target  N
    float* o2 = o1 + NN;                             // kpt_class     N x 17
    float* o3 = o2 + (size_t)NN * NKPT;              // new_protos    170 x 768

    char* ws = (char*)d_ws;
    float*  inv_f  = (float*)(ws + 0);               // N f32
    float*  pn     = (float*)(ws + 524288);          // 170x768 f32
    bf16_t* pnb    = (bf16_t*)(ws + 1048576);        // 192x768 bf16
    float*  wq_s   = (float*)(ws + 1441792);         // N f32 (sorted)
    float*  wn_s   = (float*)(ws + 1966080);         // N f32 (sorted)
    int*    perm   = (int*)  (ws + 2490368);         // N i32
    int*    rka    = (int*)  (ws + 3014656);         // N i32: rank, later reused as assign
    double* Es     = (double*)(ws + 3538944);        // N x 10 f64
    char*   zz     = ws + 14024704;                  // zero zone start
    int*    counts = (int*)  (zz + 0);
    int*    cursor = (int*)  (zz + 128);
    int*    offs   = (int*)  (zz + 256);
    double* A      = (double*)(zz + 384);
    double* T1     = (double*)(zz + 384 + 2048);
    double* T2     = (double*)(zz + 384 + 4096);
    double* colf1  = (double*)(zz + 384 + 6144);
    double* colf2  = (double*)(zz + 384 + 8192);
    double* colf3  = (double*)(zz + 384 + 10240);
    float*  nkm    = (float*) (zz + 384 + 12288);
    float*  f_raw  = (float*) (zz + 384 + 12288 + 1024);
    size_t  zz_bytes = 384 + 12288 + 1024 + (size_t)CC * DD * 4;

    hipMemsetAsync(zz, 0, zz_bytes, stream);
    k_proto_norm<<<192, 256, 0, stream>>>(protos, pn, pnb);
    k_hist<<<512, 256, 0, stream>>>(gt, counts);
    k_prefix<<<1, 64, 0, stream>>>(counts, offs);
    k_rank<<<NN / 256, 256, 0, stream>>>(gt, offs, cursor, perm, rka);
    k_prep<<<NN / 32, 256, 0, stream>>>(feats, pn, gt, perm, inv_f, Es);
    k_gemm<<<NN / 128, 256, 0, stream>>>(feats, pnb, inv_f, o0);
    k_epi2<<<NN / 64, 256, 0, stream>>>(o0, gt, conf, inv_f, rka, o2, wq_s, wn_s);
    k_colsumA<<<NKPT * CHUNKS, 256, 0, stream>>>(Es, offs, A);
    k_colf1<<<1, 256, 0, stream>>>(A, colf1);
    k_iter<<<NKPT * CHUNKS, 256, 0, stream>>>(Es, offs, counts, colf1, T1);
    k_colf<<<1, 256, 0, stream>>>(T1, colf2);
    k_iter<<<NKPT * CHUNKS, 256, 0, stream>>>(Es, offs, counts, colf2, T2);
    k_colf<<<1, 256, 0, stream>>>(T2, colf3);
    k_argmax<<<NKPT * CHUNKS, 256, 0, stream>>>(Es, offs, colf3, perm, o1, rka);
    dim3 gg(CC, GCH);
    k_gather<<<gg, 256, 0, stream>>>(feats, offs, perm, rka, wq_s, wn_s, f_raw, nkm);
    k_newproto<<<CC, 256, 0, stream>>>(f_raw, nkm, pn, o3);
}